// Round 3
// baseline (854.613 us; speedup 1.0000x reference)
//
#include <hip/hip_runtime.h>

#define N 8192
#define BATCH 8
#define CJ 256
#define NITER (N / CJ)

// Build X0[j][col] (col = 2*b + c) and transposed X0T[col][j].
__global__ __launch_bounds__(256) void pack_x0_kernel(
    const float* __restrict__ input, const float* __restrict__ hidden,
    float* __restrict__ x0, float* __restrict__ x0t) {
  int j = blockIdx.x * 256 + threadIdx.x;
  #pragma unroll
  for (int b = 0; b < BATCH; ++b) {
    float vi = input[(size_t)b * N + j];
    float vh = hidden[(size_t)b * N + j];
    x0[(size_t)j * 16 + 2 * b]     = vi;
    x0[(size_t)j * 16 + 2 * b + 1] = vh;
    x0t[(size_t)(2 * b) * N + j]     = vi;
    x0t[(size_t)(2 * b + 1) * N + j] = vh;
  }
}

// Y[i][c] = alpha * sum_j Km[i][j] * XT[c][j]  (+ beta * Xsub[i][c])
// 256 threads = 4 waves; wave owns 4 rows; lanes split j (float4 coalesced).
// No LDS staging, no main-loop barriers: X (512 KB) is L1/L2-resident --
// all waves on a CU read the same 16 KB X chunk per iteration, so L1 serves
// the re-reads. K streams from HBM into registers. Waves free-run; the
// compiler inserts precise counted vmcnt waits (no vmcnt(0) drain anywhere
// in the main loop). LDS holds only the reduction scratch (33 KB).
// Single-matrix dispatches preserve L3 reuse: K0 pass1+pass2 back-to-back
// lets pass 2 read K0 (268 MB ~ L3 size) mostly from Infinity Cache.
__global__ __launch_bounds__(256) void gemm16_kernel(
    const float* __restrict__ Km, const float* __restrict__ XT,
    const float* __restrict__ Xsub,
    float* __restrict__ Y, float* __restrict__ YT,
    float alpha, float beta) {
  __shared__ float red[256 * 33];
  const int wave = threadIdx.x >> 6;
  const int lane = threadIdx.x & 63;
  const int jl = lane * 4;
  const int i0 = blockIdx.x * 16 + wave * 4;   // this wave's first row

  float acc[4][16];
  #pragma unroll
  for (int r = 0; r < 4; ++r)
    #pragma unroll
    for (int c = 0; c < 16; ++c) acc[r][c] = 0.f;

  #pragma unroll 2
  for (int m = 0; m < NITER; ++m) {
    const int j = m * CJ + jl;
    float4 kf[4];
    #pragma unroll
    for (int r = 0; r < 4; ++r)
      kf[r] = *(const float4*)(Km + (size_t)(i0 + r) * N + j);
    #pragma unroll
    for (int c = 0; c < 16; ++c) {
      float4 x = *(const float4*)(XT + (size_t)c * N + j);
      #pragma unroll
      for (int r = 0; r < 4; ++r) {
        acc[r][c] = fmaf(kf[r].x, x.x, acc[r][c]);
        acc[r][c] = fmaf(kf[r].y, x.y, acc[r][c]);
        acc[r][c] = fmaf(kf[r].z, x.z, acc[r][c]);
        acc[r][c] = fmaf(kf[r].w, x.w, acc[r][c]);
      }
    }
  }

  // Cross-lane reduction: two passes of 32 accumulators through LDS (pad 33).
  float total = 0.f;
  #pragma unroll
  for (int r = 0; r < 2; ++r)
    #pragma unroll
    for (int c = 0; c < 16; ++c)
      red[threadIdx.x * 33 + r * 16 + c] = acc[r][c];
  __syncthreads();
  if (lane < 32) {
    float s = 0.f;
    #pragma unroll
    for (int lp = 0; lp < 64; ++lp)
      s += red[(wave * 64 + lp) * 33 + lane];
    total = s;
  }
  __syncthreads();
  #pragma unroll
  for (int r = 0; r < 2; ++r)
    #pragma unroll
    for (int c = 0; c < 16; ++c)
      red[threadIdx.x * 33 + r * 16 + c] = acc[r + 2][c];
  __syncthreads();
  if (lane >= 32) {
    float s = 0.f;
    #pragma unroll
    for (int lp = 0; lp < 64; ++lp)
      s += red[(wave * 64 + lp) * 33 + (lane - 32)];
    total = s;
  }

  const int r = lane >> 4, c = lane & 15;
  const int row = i0 + r;   // i0 already includes wave*4
  float v = alpha * total;
  if (Xsub) v += beta * Xsub[(size_t)row * 16 + c];
  Y[(size_t)row * 16 + c] = v;
  if (YT) YT[(size_t)c * N + row] = v;
}

// Bug-compatible .view gather + Linear(10->1).
__global__ __launch_bounds__(256) void out_kernel(
    const float* __restrict__ X0, const float* __restrict__ X1a,
    const float* __restrict__ X2a, const float* __restrict__ X1b,
    const float* __restrict__ X2b, const float* __restrict__ W,
    const float* __restrict__ bias, float* __restrict__ out) {
  int tid = blockIdx.x * 256 + threadIdx.x;
  int b2 = tid >> 13;
  int i  = tid & (N - 1);
  int col = 2 * (i >> 10) + (b2 & 1);
  const float* Xs[5] = {X0, X1a, X2a, X1b, X2b};
  float accv = bias[0];
  #pragma unroll
  for (int c2 = 0; c2 < 2; ++c2) {
    int n = (i & 1023) * 8 + c2 * 4 + (b2 >> 1);
    #pragma unroll
    for (int k = 0; k < 5; ++k)
      accv += W[c2 * 5 + k] * Xs[k][(size_t)n * 16 + col];
  }
  out[tid] = accv;
}

extern "C" void kernel_launch(void* const* d_in, const int* in_sizes, int n_in,
                              void* d_out, int out_size, void* d_ws, size_t ws_size,
                              hipStream_t stream) {
  const float* input  = (const float*)d_in[0];
  const float* hidden = (const float*)d_in[1];
  const float* k0     = (const float*)d_in[2];
  const float* k1     = (const float*)d_in[3];
  const float* W      = (const float*)d_in[4];
  const float* bias   = (const float*)d_in[5];
  float* out = (float*)d_out;

  float* ws = (float*)d_ws;
  const size_t SZ = (size_t)N * 16;
  float* X0   = ws;
  float* X0T  = ws + SZ;
  float* X1a  = ws + 2 * SZ;
  float* X1aT = ws + 3 * SZ;
  float* X2a  = ws + 4 * SZ;
  float* X1b  = ws + 5 * SZ;
  float* X1bT = ws + 6 * SZ;
  float* X2b  = ws + 7 * SZ;

  pack_x0_kernel<<<N / 256, 256, 0, stream>>>(input, hidden, X0, X0T);
  // Single-matrix dispatches, K0's two passes back-to-back for L3 reuse.
  gemm16_kernel<<<N / 16, 256, 0, stream>>>(k0, X0T,  nullptr, X1a, X1aT, 1.f, 0.f);
  gemm16_kernel<<<N / 16, 256, 0, stream>>>(k0, X1aT, X0,      X2a, nullptr, 2.f, -1.f);
  gemm16_kernel<<<N / 16, 256, 0, stream>>>(k1, X0T,  nullptr, X1b, X1bT, 1.f, 0.f);
  gemm16_kernel<<<N / 16, 256, 0, stream>>>(k1, X1bT, X0,      X2b, nullptr, 2.f, -1.f);

  out_kernel<<<(BATCH * N) / 256, 256, 0, stream>>>(
      X0, X1a, X2a, X1b, X2b, W, bias, out);
}

// Round 4
// 824.723 us; speedup vs baseline: 1.0362x; 1.0362x over previous
//
#include <hip/hip_runtime.h>

#define N 8192
#define BATCH 8
#define CJ 256
#define NITER (N / CJ)   // 32
#define ROWS 8           // rows per block
#define RPW 2            // rows per wave

// Build X0[j][col] (col = 2*b + c) and transposed X0T[col][j].
__global__ __launch_bounds__(256) void pack_x0_kernel(
    const float* __restrict__ input, const float* __restrict__ hidden,
    float* __restrict__ x0, float* __restrict__ x0t) {
  int j = blockIdx.x * 256 + threadIdx.x;
  #pragma unroll
  for (int b = 0; b < BATCH; ++b) {
    float vi = input[(size_t)b * N + j];
    float vh = hidden[(size_t)b * N + j];
    x0[(size_t)j * 16 + 2 * b]     = vi;
    x0[(size_t)j * 16 + 2 * b + 1] = vh;
    x0t[(size_t)(2 * b) * N + j]     = vi;
    x0t[(size_t)(2 * b + 1) * N + j] = vh;
  }
}

// Y[i][c] = alpha * sum_j Km[i][j] * XT[c][j]  (+ beta * Xsub[i][c])
// 8 rows/block -> 1024 blocks -> 4 blocks/CU (proven +57% streaming vs 2).
// 256 threads = 4 waves; wave owns 2 rows; lanes split j (float4 coalesced).
// X chunk (16x256) double-buffered in LDS via global_load_lds (width=16).
// K prefetched DEPTH-2 into a 4-slot register ring (static indices via
// unroll-4). Main loop uses raw s_barrier + counted s_waitcnt vmcnt(2):
// the X stage for chunk m+1 (oldest 4 vmem ops) is drained, the K loads
// for chunk m+2 (newest 2) stay in flight across the barrier -- the HBM
// queue never empties (no vmcnt(0) drain in the main loop).
// LDS: Xs (32 KB) unioned with reduction scratch (33 KB) -> 33 KB/block.
__global__ __launch_bounds__(256, 4) void gemm8_kernel(
    const float* __restrict__ Km, const float* __restrict__ XT,
    const float* __restrict__ Xsub,
    float* __restrict__ Y, float* __restrict__ YT,
    float alpha, float beta) {
  __shared__ float smem[256 * 33];                 // 33.8 KB
  float (*Xs)[16][CJ] = (float (*)[16][CJ])smem;   // [2][16][256] = 32 KB
  float* red = smem;

  const int wave = threadIdx.x >> 6;
  const int lane = threadIdx.x & 63;
  const int jl = lane * 4;
  const int i0 = blockIdx.x * ROWS + wave * RPW;   // this wave's first row

  float acc[RPW][16];
  #pragma unroll
  for (int r = 0; r < RPW; ++r)
    #pragma unroll
    for (int c = 0; c < 16; ++c) acc[r][c] = 0.f;

  float4 kf[4][RPW];  // K ring: slot s holds chunk m with m&3==s

  // Prologue: stage X chunk 0, load K chunks 0 and 1, full drain once.
  #pragma unroll
  for (int c2 = 0; c2 < 4; ++c2) {
    int c = c2 * 4 + wave;
    const float* gp = XT + (size_t)c * N + jl;
    __builtin_amdgcn_global_load_lds(
        (__attribute__((address_space(1))) void*)gp,
        (__attribute__((address_space(3))) void*)&Xs[0][c][0], 16, 0, 0);
  }
  asm volatile("" ::: "memory");
  #pragma unroll
  for (int r = 0; r < RPW; ++r) {
    kf[0][r] = *(const float4*)(Km + (size_t)(i0 + r) * N + jl);
    kf[1][r] = *(const float4*)(Km + (size_t)(i0 + r) * N + CJ + jl);
  }
  __syncthreads();  // one-time full drain; steady state never drains to 0

  for (int g = 0; g < NITER / 4; ++g) {
    #pragma unroll
    for (int mm = 0; mm < 4; ++mm) {
      const int m = g * 4 + mm;
      const int p = mm & 1;                        // static buffer index
      // 1) Issue X stage for chunk m+1 (these become the OLDEST vmem ops).
      if (m + 1 < NITER) {
        int jn = (m + 1) * CJ + jl;
        #pragma unroll
        for (int c2 = 0; c2 < 4; ++c2) {
          int c = c2 * 4 + wave;
          const float* gp = XT + (size_t)c * N + jn;
          __builtin_amdgcn_global_load_lds(
              (__attribute__((address_space(1))) void*)gp,
              (__attribute__((address_space(3))) void*)&Xs[p ^ 1][c][0],
              16, 0, 0);
        }
      }
      asm volatile("" ::: "memory");  // pin issue order: X stage before K
      // 2) Issue K loads for chunk m+2 (depth-2 prefetch, static slot).
      if (m + 2 < NITER) {
        int j2 = (m + 2) * CJ + jl;
        #pragma unroll
        for (int r = 0; r < RPW; ++r)
          kf[(mm + 2) & 3][r] =
              *(const float4*)(Km + (size_t)(i0 + r) * N + j2);
      }
      // 3) Compute chunk m from LDS buffer p and K slot mm.
      #pragma unroll
      for (int c = 0; c < 16; ++c) {
        float4 x = *(const float4*)&Xs[p][c][jl];
        #pragma unroll
        for (int r = 0; r < RPW; ++r) {
          acc[r][c] = fmaf(kf[mm][r].x, x.x, acc[r][c]);
          acc[r][c] = fmaf(kf[mm][r].y, x.y, acc[r][c]);
          acc[r][c] = fmaf(kf[mm][r].z, x.z, acc[r][c]);
          acc[r][c] = fmaf(kf[mm][r].w, x.w, acc[r][c]);
        }
      }
      // 4) Counted wait + raw barrier: X(m+1) staged (oldest 4 + leftover
      //    K(m+1)x2 drained); K(m+2)x2 stay in flight across the barrier.
      if (m + 1 < NITER) {
        if (m + 2 < NITER)
          asm volatile("s_waitcnt vmcnt(2)" ::: "memory");
        else
          asm volatile("s_waitcnt vmcnt(0)" ::: "memory");
        __builtin_amdgcn_s_barrier();
        __builtin_amdgcn_sched_barrier(0);
      }
    }
  }

  // Cross-lane reduction: 32 accumulators per thread through LDS (pad 33).
  __syncthreads();  // all waves done reading Xs before red overwrites it
  #pragma unroll
  for (int r = 0; r < RPW; ++r)
    #pragma unroll
    for (int c = 0; c < 16; ++c)
      red[threadIdx.x * 33 + r * 16 + c] = acc[r][c];
  __syncthreads();
  if (lane < 32) {
    float s = 0.f;
    #pragma unroll
    for (int lp = 0; lp < 64; ++lp)
      s += red[(wave * 64 + lp) * 33 + lane];
    const int r = lane >> 4, c = lane & 15;
    const int row = i0 + r;
    float v = alpha * s;
    if (Xsub) v += beta * Xsub[(size_t)row * 16 + c];
    Y[(size_t)row * 16 + c] = v;
    if (YT) YT[(size_t)c * N + row] = v;
  }
}

// Bug-compatible .view gather + Linear(10->1).
__global__ __launch_bounds__(256) void out_kernel(
    const float* __restrict__ X0, const float* __restrict__ X1a,
    const float* __restrict__ X2a, const float* __restrict__ X1b,
    const float* __restrict__ X2b, const float* __restrict__ W,
    const float* __restrict__ bias, float* __restrict__ out) {
  int tid = blockIdx.x * 256 + threadIdx.x;
  int b2 = tid >> 13;
  int i  = tid & (N - 1);
  int col = 2 * (i >> 10) + (b2 & 1);
  const float* Xs[5] = {X0, X1a, X2a, X1b, X2b};
  float accv = bias[0];
  #pragma unroll
  for (int c2 = 0; c2 < 2; ++c2) {
    int n = (i & 1023) * 8 + c2 * 4 + (b2 >> 1);
    #pragma unroll
    for (int k = 0; k < 5; ++k)
      accv += W[c2 * 5 + k] * Xs[k][(size_t)n * 16 + col];
  }
  out[tid] = accv;
}

extern "C" void kernel_launch(void* const* d_in, const int* in_sizes, int n_in,
                              void* d_out, int out_size, void* d_ws, size_t ws_size,
                              hipStream_t stream) {
  const float* input  = (const float*)d_in[0];
  const float* hidden = (const float*)d_in[1];
  const float* k0     = (const float*)d_in[2];
  const float* k1     = (const float*)d_in[3];
  const float* W      = (const float*)d_in[4];
  const float* bias   = (const float*)d_in[5];
  float* out = (float*)d_out;

  float* ws = (float*)d_ws;
  const size_t SZ = (size_t)N * 16;
  float* X0   = ws;
  float* X0T  = ws + SZ;
  float* X1a  = ws + 2 * SZ;
  float* X1aT = ws + 3 * SZ;
  float* X2a  = ws + 4 * SZ;
  float* X1b  = ws + 5 * SZ;
  float* X1bT = ws + 6 * SZ;
  float* X2b  = ws + 7 * SZ;

  pack_x0_kernel<<<N / 256, 256, 0, stream>>>(input, hidden, X0, X0T);
  // Single-matrix dispatches; K0's two passes back-to-back for L3 reuse.
  gemm8_kernel<<<N / ROWS, 256, 0, stream>>>(k0, X0T,  nullptr, X1a, X1aT, 1.f, 0.f);
  gemm8_kernel<<<N / ROWS, 256, 0, stream>>>(k0, X1aT, X0,      X2a, nullptr, 2.f, -1.f);
  gemm8_kernel<<<N / ROWS, 256, 0, stream>>>(k1, X0T,  nullptr, X1b, X1bT, 1.f, 0.f);
  gemm8_kernel<<<N / ROWS, 256, 0, stream>>>(k1, X1bT, X0,      X2b, nullptr, 2.f, -1.f);

  out_kernel<<<(BATCH * N) / 256, 256, 0, stream>>>(
      X0, X1a, X2a, X1b, X2b, W, bias, out);
}

// Round 6
// 755.179 us; speedup vs baseline: 1.1317x; 1.0921x over previous
//
#include <hip/hip_runtime.h>

#define N 8192
#define BATCH 8
#define CJ 256
#define JH 4096              // j-range per block (half of N)
#define NITER_H (JH / CJ)    // 16 chunks per block

// Build X0[j][col] (col = 2*b + c) and transposed X0T[col][j].
__global__ __launch_bounds__(256) void pack_x0_kernel(
    const float* __restrict__ input, const float* __restrict__ hidden,
    float* __restrict__ x0, float* __restrict__ x0t) {
  int j = blockIdx.x * 256 + threadIdx.x;
  #pragma unroll
  for (int b = 0; b < BATCH; ++b) {
    float vi = input[(size_t)b * N + j];
    float vh = hidden[(size_t)b * N + j];
    x0[(size_t)j * 16 + 2 * b]     = vi;
    x0[(size_t)j * 16 + 2 * b + 1] = vh;
    x0t[(size_t)(2 * b) * N + j]     = vi;
    x0t[(size_t)(2 * b + 1) * N + j] = vh;
  }
}

// Split-j partial GEMM: Yp[i][c] = sum_{j in half h} Km[i][j] * XT[c][j].
// Grid = 512 row-groups x 2 j-halves = 1024 blocks -> 4 blocks/CU
// (LDS unioned to 33.8 KB, __launch_bounds__(256,4)).
// Inner loop is the proven round-0/round-1 structure verbatim: 4 waves,
// wave owns 4 rows, X chunk (16x256) double-buffered in LDS via
// global_load_lds (width=16), K depth-1 prefetched into registers,
// one __syncthreads per chunk (compiler-scheduled; no asm pinning).
// Single-matrix dispatches preserve the K0/K1 L3 pass-2 reuse.
__global__ __launch_bounds__(256, 4) void gemm16s_kernel(
    const float* __restrict__ Km, const float* __restrict__ XT,
    float* __restrict__ Yp0, float* __restrict__ Yp1) {
  // Union: Xs = 2*16*256 floats (32 KB); red = 256*33 floats (33.8 KB).
  // Live ranges disjoint (separated by a __syncthreads).
  __shared__ float smem[256 * 33];
  float (*Xs)[16][CJ] = (float (*)[16][CJ])smem;
  float* red = smem;

  const int wave = threadIdx.x >> 6;
  const int lane = threadIdx.x & 63;
  const int jl = lane * 4;
  const int h  = blockIdx.x & 1;            // j-half
  const int g  = blockIdx.x >> 1;           // row-group
  const int i0 = g * 16 + wave * 4;         // this wave's first row
  const int j0 = h * JH;                    // this block's j base
  float* __restrict__ Yp = h ? Yp1 : Yp0;

  float acc[4][16];
  #pragma unroll
  for (int r = 0; r < 4; ++r)
    #pragma unroll
    for (int c = 0; c < 16; ++c) acc[r][c] = 0.f;

  // Stage chunk 0: each wave async-copies 4 X columns (1 KB each) to LDS.
  #pragma unroll
  for (int c2 = 0; c2 < 4; ++c2) {
    int c = c2 * 4 + wave;
    const float* gp = XT + (size_t)c * N + j0 + jl;
    __builtin_amdgcn_global_load_lds(
        (__attribute__((address_space(1))) void*)gp,
        (__attribute__((address_space(3))) void*)&Xs[0][c][0], 16, 0, 0);
  }
  float4 kfA[4], kfB[4];
  #pragma unroll
  for (int r = 0; r < 4; ++r)
    kfA[r] = *(const float4*)(Km + (size_t)(i0 + r) * N + j0 + jl);
  __syncthreads();

  int p = 0;
  for (int m = 0; m < NITER_H; ++m) {
    // Prefetch chunk m+1 (async LDS stage + K regs) before computing chunk m.
    if (m + 1 < NITER_H) {
      int jn = j0 + (m + 1) * CJ + jl;
      #pragma unroll
      for (int c2 = 0; c2 < 4; ++c2) {
        int c = c2 * 4 + wave;
        const float* gp = XT + (size_t)c * N + jn;
        __builtin_amdgcn_global_load_lds(
            (__attribute__((address_space(1))) void*)gp,
            (__attribute__((address_space(3))) void*)&Xs[p ^ 1][c][0], 16, 0, 0);
      }
      #pragma unroll
      for (int r = 0; r < 4; ++r)
        kfB[r] = *(const float4*)(Km + (size_t)(i0 + r) * N + jn);
    }
    #pragma unroll
    for (int c = 0; c < 16; ++c) {
      float4 x = *(const float4*)&Xs[p][c][jl];
      #pragma unroll
      for (int r = 0; r < 4; ++r) {
        acc[r][c] = fmaf(kfA[r].x, x.x, acc[r][c]);
        acc[r][c] = fmaf(kfA[r].y, x.y, acc[r][c]);
        acc[r][c] = fmaf(kfA[r].z, x.z, acc[r][c]);
        acc[r][c] = fmaf(kfA[r].w, x.w, acc[r][c]);
      }
    }
    __syncthreads();  // drains vmcnt: chunk m+1 LDS stage + kfB complete
    if (m + 1 < NITER_H) {
      #pragma unroll
      for (int r = 0; r < 4; ++r) kfA[r] = kfB[r];
    }
    p ^= 1;
  }

  // Cross-lane reduction: two passes of 32 accumulators through LDS (pad 33).
  float total = 0.f;
  #pragma unroll
  for (int r = 0; r < 2; ++r)
    #pragma unroll
    for (int c = 0; c < 16; ++c)
      red[threadIdx.x * 33 + r * 16 + c] = acc[r][c];
  __syncthreads();
  if (lane < 32) {
    float s = 0.f;
    #pragma unroll
    for (int lp = 0; lp < 64; ++lp)
      s += red[(wave * 64 + lp) * 33 + lane];
    total = s;
  }
  __syncthreads();
  #pragma unroll
  for (int r = 0; r < 2; ++r)
    #pragma unroll
    for (int c = 0; c < 16; ++c)
      red[threadIdx.x * 33 + r * 16 + c] = acc[r + 2][c];
  __syncthreads();
  if (lane >= 32) {
    float s = 0.f;
    #pragma unroll
    for (int lp = 0; lp < 64; ++lp)
      s += red[(wave * 64 + lp) * 33 + (lane - 32)];
    total = s;
  }

  const int r = lane >> 4, c = lane & 15;
  const int row = i0 + r;   // i0 already includes wave*4
  Yp[(size_t)row * 16 + c] = total;   // raw partial; combine applies alpha/beta
}

// Merge the two j-half partials, apply alpha/beta/Xsub, emit Y and YT.
// 2.5 MB of traffic -> a few microseconds.
__global__ __launch_bounds__(256) void combine_kernel(
    const float* __restrict__ Yp0, const float* __restrict__ Yp1,
    const float* __restrict__ Xsub,
    float* __restrict__ Y, float* __restrict__ YT,
    float alpha, float beta) {
  int t = blockIdx.x * 256 + threadIdx.x;   // t = row*16 + c
  float v = alpha * (Yp0[t] + Yp1[t]);
  if (Xsub) v += beta * Xsub[t];
  Y[t] = v;
  if (YT) YT[(size_t)(t & 15) * N + (t >> 4)] = v;
}

// Bug-compatible .view gather + Linear(10->1).
__global__ __launch_bounds__(256) void out_kernel(
    const float* __restrict__ X0, const float* __restrict__ X1a,
    const float* __restrict__ X2a, const float* __restrict__ X1b,
    const float* __restrict__ X2b, const float* __restrict__ W,
    const float* __restrict__ bias, float* __restrict__ out) {
  int tid = blockIdx.x * 256 + threadIdx.x;
  int b2 = tid >> 13;
  int i  = tid & (N - 1);
  int col = 2 * (i >> 10) + (b2 & 1);
  const float* Xs[5] = {X0, X1a, X2a, X1b, X2b};
  float accv = bias[0];
  #pragma unroll
  for (int c2 = 0; c2 < 2; ++c2) {
    int n = (i & 1023) * 8 + c2 * 4 + (b2 >> 1);
    #pragma unroll
    for (int k = 0; k < 5; ++k)
      accv += W[c2 * 5 + k] * Xs[k][(size_t)n * 16 + col];
  }
  out[tid] = accv;
}

extern "C" void kernel_launch(void* const* d_in, const int* in_sizes, int n_in,
                              void* d_out, int out_size, void* d_ws, size_t ws_size,
                              hipStream_t stream) {
  const float* input  = (const float*)d_in[0];
  const float* hidden = (const float*)d_in[1];
  const float* k0     = (const float*)d_in[2];
  const float* k1     = (const float*)d_in[3];
  const float* W      = (const float*)d_in[4];
  const float* bias   = (const float*)d_in[5];
  float* out = (float*)d_out;

  float* ws = (float*)d_ws;
  const size_t SZ = (size_t)N * 16;
  float* X0   = ws;
  float* X0T  = ws + SZ;
  float* X1a  = ws + 2 * SZ;
  float* X1aT = ws + 3 * SZ;
  float* X2a  = ws + 4 * SZ;
  float* X1b  = ws + 5 * SZ;
  float* X1bT = ws + 6 * SZ;
  float* X2b  = ws + 7 * SZ;
  float* P0   = ws + 8 * SZ;
  float* P1   = ws + 9 * SZ;

  const int GB = 2 * (N / 16);          // 1024 blocks per GEMM
  const int CB = (N * 16) / 256;        // 512 blocks per combine

  pack_x0_kernel<<<N / 256, 256, 0, stream>>>(input, hidden, X0, X0T);
  // Single-matrix dispatches; K0's two passes back-to-back for L3 reuse.
  gemm16s_kernel<<<GB, 256, 0, stream>>>(k0, X0T, P0, P1);
  combine_kernel<<<CB, 256, 0, stream>>>(P0, P1, nullptr, X1a, X1aT, 1.f, 0.f);
  gemm16s_kernel<<<GB, 256, 0, stream>>>(k0, X1aT, P0, P1);
  combine_kernel<<<CB, 256, 0, stream>>>(P0, P1, X0, X2a, nullptr, 2.f, -1.f);
  gemm16s_kernel<<<GB, 256, 0, stream>>>(k1, X0T, P0, P1);
  combine_kernel<<<CB, 256, 0, stream>>>(P0, P1, nullptr, X1b, X1bT, 1.f, 0.f);
  gemm16s_kernel<<<GB, 256, 0, stream>>>(k1, X1bT, P0, P1);
  combine_kernel<<<CB, 256, 0, stream>>>(P0, P1, X0, X2b, nullptr, 2.f, -1.f);

  out_kernel<<<(BATCH * N) / 256, 256, 0, stream>>>(
      X0, X1a, X2a, X1b, X2b, W, bias, out);
}

// Round 7
// 653.654 us; speedup vs baseline: 1.3074x; 1.1553x over previous
//
#include <hip/hip_runtime.h>

#define N 8192
#define BATCH 8
#define CJ 256
#define NITER (N / CJ)

// Build X0[j][col] (col = 2*b + c) and transposed X0T[col][j].
__global__ __launch_bounds__(256) void pack_x0_kernel(
    const float* __restrict__ input, const float* __restrict__ hidden,
    float* __restrict__ x0, float* __restrict__ x0t) {
  int j = blockIdx.x * 256 + threadIdx.x;
  #pragma unroll
  for (int b = 0; b < BATCH; ++b) {
    float vi = input[(size_t)b * N + j];
    float vh = hidden[(size_t)b * N + j];
    x0[(size_t)j * 16 + 2 * b]     = vi;
    x0[(size_t)j * 16 + 2 * b + 1] = vh;
    x0t[(size_t)(2 * b) * N + j]     = vi;
    x0t[(size_t)(2 * b + 1) * N + j] = vh;
  }
}

// Y[i][c] = alpha * sum_j Km[i][j] * XT[c][j]  (+ beta * Xsub[i][c])
// Round-0 proven structure: 256 threads = 4 waves; wave owns 4 rows; lanes
// split j (float4 coalesced). X chunk (16 x 256) staged to LDS via
// global_load_lds (async, width=16), double-buffered; K prefetched one
// chunk ahead into registers.
// REV: j-chunk iteration order. All blocks of a pass sweep j together, so
// L3 recency is ordered by chunk index. A forward pass ends with L3 holding
// the TAIL chunks of all rows; the next pass over the same matrix must run
// REVERSED (chunks 31->0) to consume L3 in recency order (~90% hits) instead
// of chasing evictions (0% hits, LRU streaming pathology).
template <int REV>
__global__ __launch_bounds__(256) void gemm16_kernel(
    const float* __restrict__ Km, const float* __restrict__ XT,
    const float* __restrict__ Xsub,
    float* __restrict__ Y, float* __restrict__ YT,
    float alpha, float beta) {
  __shared__ float Xs[2][16][CJ];
  __shared__ float red[256 * 33];
  const int wave = threadIdx.x >> 6;
  const int lane = threadIdx.x & 63;
  const int jl = lane * 4;
  const int i0 = blockIdx.x * 16 + wave * 4;   // this wave's first row

  float acc[4][16];
  #pragma unroll
  for (int r = 0; r < 4; ++r)
    #pragma unroll
    for (int c = 0; c < 16; ++c) acc[r][c] = 0.f;

  // Chunk index for step m: REV ? NITER-1-m : m.
  const int q0 = REV ? (NITER - 1) : 0;

  // Stage chunk q0: each wave async-copies 4 X columns (1 KB each) to LDS.
  #pragma unroll
  for (int c2 = 0; c2 < 4; ++c2) {
    int c = c2 * 4 + wave;
    const float* gp = XT + (size_t)c * N + q0 * CJ + jl;
    __builtin_amdgcn_global_load_lds(
        (__attribute__((address_space(1))) void*)gp,
        (__attribute__((address_space(3))) void*)&Xs[0][c][0], 16, 0, 0);
  }
  float4 kfA[4], kfB[4];
  #pragma unroll
  for (int r = 0; r < 4; ++r)
    kfA[r] = *(const float4*)(Km + (size_t)(i0 + r) * N + q0 * CJ + jl);
  __syncthreads();

  int p = 0;
  for (int m = 0; m < NITER; ++m) {
    // Prefetch chunk for step m+1 (async LDS stage + K regs) before
    // computing step m's chunk.
    if (m + 1 < NITER) {
      const int qn = REV ? (NITER - 2 - m) : (m + 1);
      int jn = qn * CJ + jl;
      #pragma unroll
      for (int c2 = 0; c2 < 4; ++c2) {
        int c = c2 * 4 + wave;
        const float* gp = XT + (size_t)c * N + jn;
        __builtin_amdgcn_global_load_lds(
            (__attribute__((address_space(1))) void*)gp,
            (__attribute__((address_space(3))) void*)&Xs[p ^ 1][c][0], 16, 0, 0);
      }
      #pragma unroll
      for (int r = 0; r < 4; ++r)
        kfB[r] = *(const float4*)(Km + (size_t)(i0 + r) * N + jn);
    }
    #pragma unroll
    for (int c = 0; c < 16; ++c) {
      float4 x = *(const float4*)&Xs[p][c][jl];
      #pragma unroll
      for (int r = 0; r < 4; ++r) {
        acc[r][c] = fmaf(kfA[r].x, x.x, acc[r][c]);
        acc[r][c] = fmaf(kfA[r].y, x.y, acc[r][c]);
        acc[r][c] = fmaf(kfA[r].z, x.z, acc[r][c]);
        acc[r][c] = fmaf(kfA[r].w, x.w, acc[r][c]);
      }
    }
    __syncthreads();  // drains vmcnt: next chunk LDS stage + kfB complete
    if (m + 1 < NITER) {
      #pragma unroll
      for (int r = 0; r < 4; ++r) kfA[r] = kfB[r];
    }
    p ^= 1;
  }

  // Cross-lane reduction: two passes of 32 accumulators through LDS (pad 33).
  float total = 0.f;
  #pragma unroll
  for (int r = 0; r < 2; ++r)
    #pragma unroll
    for (int c = 0; c < 16; ++c)
      red[threadIdx.x * 33 + r * 16 + c] = acc[r][c];
  __syncthreads();
  if (lane < 32) {
    float s = 0.f;
    #pragma unroll
    for (int lp = 0; lp < 64; ++lp)
      s += red[(wave * 64 + lp) * 33 + lane];
    total = s;
  }
  __syncthreads();
  #pragma unroll
  for (int r = 0; r < 2; ++r)
    #pragma unroll
    for (int c = 0; c < 16; ++c)
      red[threadIdx.x * 33 + r * 16 + c] = acc[r + 2][c];
  __syncthreads();
  if (lane >= 32) {
    float s = 0.f;
    #pragma unroll
    for (int lp = 0; lp < 64; ++lp)
      s += red[(wave * 64 + lp) * 33 + (lane - 32)];
    total = s;
  }

  const int r = lane >> 4, c = lane & 15;
  const int row = i0 + r;   // i0 already includes wave*4
  float v = alpha * total;
  if (Xsub) v += beta * Xsub[(size_t)row * 16 + c];
  Y[(size_t)row * 16 + c] = v;
  if (YT) YT[(size_t)c * N + row] = v;
}

// Bug-compatible .view gather + Linear(10->1).
__global__ __launch_bounds__(256) void out_kernel(
    const float* __restrict__ X0, const float* __restrict__ X1a,
    const float* __restrict__ X2a, const float* __restrict__ X1b,
    const float* __restrict__ X2b, const float* __restrict__ W,
    const float* __restrict__ bias, float* __restrict__ out) {
  int tid = blockIdx.x * 256 + threadIdx.x;
  int b2 = tid >> 13;
  int i  = tid & (N - 1);
  int col = 2 * (i >> 10) + (b2 & 1);
  const float* Xs[5] = {X0, X1a, X2a, X1b, X2b};
  float accv = bias[0];
  #pragma unroll
  for (int c2 = 0; c2 < 2; ++c2) {
    int n = (i & 1023) * 8 + c2 * 4 + (b2 >> 1);
    #pragma unroll
    for (int k = 0; k < 5; ++k)
      accv += W[c2 * 5 + k] * Xs[k][(size_t)n * 16 + col];
  }
  out[tid] = accv;
}

extern "C" void kernel_launch(void* const* d_in, const int* in_sizes, int n_in,
                              void* d_out, int out_size, void* d_ws, size_t ws_size,
                              hipStream_t stream) {
  const float* input  = (const float*)d_in[0];
  const float* hidden = (const float*)d_in[1];
  const float* k0     = (const float*)d_in[2];
  const float* k1     = (const float*)d_in[3];
  const float* W      = (const float*)d_in[4];
  const float* bias   = (const float*)d_in[5];
  float* out = (float*)d_out;

  float* ws = (float*)d_ws;
  const size_t SZ = (size_t)N * 16;
  float* X0   = ws;
  float* X0T  = ws + SZ;
  float* X1a  = ws + 2 * SZ;
  float* X1aT = ws + 3 * SZ;
  float* X2a  = ws + 4 * SZ;
  float* X1b  = ws + 5 * SZ;
  float* X1bT = ws + 6 * SZ;
  float* X2b  = ws + 7 * SZ;

  pack_x0_kernel<<<N / 256, 256, 0, stream>>>(input, hidden, X0, X0T);
  // Pass 1 forward (cold); pass 2 REVERSED j-order to consume L3 in recency
  // order (pass 1 leaves L3 holding the tail j-chunks of all K rows).
  gemm16_kernel<0><<<N / 16, 256, 0, stream>>>(k0, X0T,  nullptr, X1a, X1aT, 1.f, 0.f);
  gemm16_kernel<1><<<N / 16, 256, 0, stream>>>(k0, X1aT, X0,      X2a, nullptr, 2.f, -1.f);
  gemm16_kernel<0><<<N / 16, 256, 0, stream>>>(k1, X0T,  nullptr, X1b, X1bT, 1.f, 0.f);
  gemm16_kernel<1><<<N / 16, 256, 0, stream>>>(k1, X1bT, X0,      X2b, nullptr, 2.f, -1.f);

  out_kernel<<<(BATCH * N) / 256, 256, 0, stream>>>(
      X0, X1a, X2a, X1b, X2b, W, bias, out);
}